// Round 10
// baseline (218.726 us; speedup 1.0000x reference)
//
#include <hip/hip_runtime.h>
#include <hip/hip_bf16.h>

#define N_NODES 50000
#define N_EDGES 800000
#define D_IN    512
#define D_OUT   256
#define NBLK_SCAN ((N_NODES + 1023) / 1024)   // 49
#define GEMM_NWG (((N_NODES + 127) / 128) * 2)  // 782
#define GEMM_Q   (GEMM_NWG / 8)                  // 97
#define GEMM_R   (GEMM_NWG % 8)                  // 6

typedef short s8v  __attribute__((ext_vector_type(8)));
typedef float f32x4 __attribute__((ext_vector_type(4)));

__device__ __forceinline__ unsigned short bf16b(float f) {
    __hip_bfloat16 h = __float2bfloat16(f);
    return *reinterpret_cast<unsigned short*>(&h);
}
__device__ __forceinline__ float bflo(unsigned u) { return __uint_as_float(u << 16); }
__device__ __forceinline__ float bfhi(unsigned u) { return __uint_as_float(u & 0xffff0000u); }

// global -> LDS direct copy, 16B per lane; LDS dest arg = wave-uniform base,
// HW adds lane*16.
#define GLD16(gp, lp)                                                           \
    __builtin_amdgcn_global_load_lds(                                           \
        (const __attribute__((address_space(1))) unsigned int*)(const void*)(gp),\
        (__attribute__((address_space(3))) unsigned int*)(void*)(lp), 16, 0, 0)

__device__ __forceinline__ int wave_incl_scan(int v, int lane) {
    #pragma unroll
    for (int d = 1; d < 64; d <<= 1) {
        int u = __shfl_up(v, d, 64);
        if (lane >= d) v += u;
    }
    return v;
}

// ============ CSR build ============

__global__ void k_count(const int* __restrict__ col, int* __restrict__ cnt) {
    int i = blockIdx.x * 256 + threadIdx.x;
    if (i < N_EDGES) atomicAdd(&cnt[col[i]], 1);
}

__launch_bounds__(256)
__global__ void k_scan1(const int* __restrict__ cnt, int* __restrict__ bsum) {
    const int t = threadIdx.x, b = blockIdx.x;
    const int idx = b * 1024 + t * 4;
    int4 v = make_int4(0, 0, 0, 0);
    if (idx < N_NODES) v = *(const int4*)&cnt[idx];
    int s = v.x + v.y + v.z + v.w;
    #pragma unroll
    for (int d = 1; d < 64; d <<= 1) s += __shfl_xor(s, d, 64);
    __shared__ int ws[4];
    if ((t & 63) == 0) ws[t >> 6] = s;
    __syncthreads();
    if (t == 0) bsum[b] = ws[0] + ws[1] + ws[2] + ws[3];
}

__global__ void k_scan2(const int* __restrict__ bsum, int* __restrict__ boff) {
    const int t = threadIdx.x;   // 64
    int v = (t < NBLK_SCAN) ? bsum[t] : 0;
    int inc = wave_incl_scan(v, t);
    if (t < NBLK_SCAN) boff[t] = inc - v;
}

__launch_bounds__(256)
__global__ void k_scan3(const int* __restrict__ cnt, const int* __restrict__ boff,
                        int* __restrict__ row_ptr, float* __restrict__ dinv,
                        int* __restrict__ cursor) {
    const int t = threadIdx.x, b = blockIdx.x;
    const int lane = t & 63, wv = t >> 6;
    const int idx = b * 1024 + t * 4;
    int4 v = make_int4(0, 0, 0, 0);
    if (idx < N_NODES) v = *(const int4*)&cnt[idx];
    int s = v.x + v.y + v.z + v.w;
    int isc = wave_incl_scan(s, lane);
    __shared__ int wsum[4];
    if (lane == 63) wsum[wv] = isc;
    __syncthreads();
    int off = boff[b];
    #pragma unroll
    for (int i = 0; i < 4; ++i)
        if (i < wv) off += wsum[i];
    int p0 = off + isc - s;
    int p1 = p0 + v.x;
    int p2 = p1 + v.y;
    int p3 = p2 + v.z;
    if (idx < N_NODES) {
        row_ptr[idx + 0] = p0; cursor[idx + 0] = p0; dinv[idx + 0] = rsqrtf(1.f + (float)v.x);
        row_ptr[idx + 1] = p1; cursor[idx + 1] = p1; dinv[idx + 1] = rsqrtf(1.f + (float)v.y);
        row_ptr[idx + 2] = p2; cursor[idx + 2] = p2; dinv[idx + 2] = rsqrtf(1.f + (float)v.z);
        row_ptr[idx + 3] = p3; cursor[idx + 3] = p3; dinv[idx + 3] = rsqrtf(1.f + (float)v.w);
    }
    if (b == 0 && t == 0) row_ptr[N_NODES] = N_EDGES;
}

__global__ void k_fill(const int* __restrict__ row, const int* __restrict__ col,
                       int* __restrict__ cursor, int* __restrict__ csr_src) {
    int i = blockIdx.x * 256 + threadIdx.x;
    if (i < N_EDGES) {
        int pos = atomicAdd(&cursor[col[i]], 1);
        csr_src[pos] = row[i];
    }
}

// ============ W transpose + bf16 convert ============
__global__ void k_wt(const float* __restrict__ W, unsigned short* __restrict__ Wt) {
    int k = blockIdx.x;      // 512
    int n = threadIdx.x;     // 256
    Wt[(size_t)n * D_IN + k] = bf16b(W[(size_t)k * D_OUT + n]);
}

// ============ MFMA GEMM: yb = bf16(dinv[r] * (x @ W)) ============
// 2-phase double-buffered BK=32 (T3-minimum): issue next tile's global_load_lds
// BEFORE computing current tile; ONE barrier per step (its vmcnt drain retires
// the prefetch) -> HBM latency hides under the 16-MFMA compute phase.
// Conflict rule (R7-vs-R8 data): b128 conflicts count per 16-lane quarter-wave;
// need <=2 lanes per 16B slot-position per quarter.
//  A rows = 128B (8 slots): stored slot s of row r = logical s^(r&7)  -> free.
//  B rows = 64B (4 slots):  stored slot s of row r = logical s^((r>>1)&3) -> free.
__launch_bounds__(256)
__global__ void k_gemm(const float* __restrict__ A,            // [N_NODES,512] fp32
                       const unsigned short* __restrict__ Wt,  // [256,512] bf16
                       const float* __restrict__ dinv,
                       unsigned short* __restrict__ yb)        // [N_NODES,256] bf16
{
    __shared__ __align__(16) float          As[2 * 128 * 32];   // 32 KB (2 bufs)
    __shared__ __align__(16) unsigned short Bs[2 * 128 * 32];   // 16 KB (2 bufs)

    // bijective XCD swizzle (m204)
    int orig = blockIdx.x;
    int xcd = orig % 8, pos = orig / 8;
    int wg = (xcd < GEMM_R) ? xcd * (GEMM_Q + 1) + pos
                            : GEMM_R * (GEMM_Q + 1) + (xcd - GEMM_R) * GEMM_Q + pos;
    const int nt = wg & 1;
    const int mt = wg >> 1;
    const int m0 = mt * 128;
    const int n0 = nt * 128;

    const int t  = threadIdx.x;
    const int w  = t >> 6;
    const int l  = t & 63;
    const int wm = (w >> 1) * 64;
    const int wn = (w & 1) * 64;
    const int lr = l & 15;
    const int lk = l >> 4;

    // ---- A staging: 4 GLDs/wave, GLD i covers LDS rows w*32+i*8+(l>>3),
    // stored slot l&7 <- source slot (l&7)^(l>>3)
    size_t aoff[4];
    #pragma unroll
    for (int i = 0; i < 4; ++i) {
        int r = m0 + w * 32 + i * 8 + (l >> 3);
        if (r >= N_NODES) r = 0;                 // tail clamp; outputs guarded
        aoff[i] = (size_t)r * D_IN + ((l & 7) ^ (l >> 3)) * 4;   // float units
    }
    // ---- B staging: 2 GLDs/wave, GLD i covers rows w*32+i*16+(l>>2),
    // stored slot l&3 <- source slot (l&3)^((l>>3)&3)
    size_t boff[2];
    #pragma unroll
    for (int i = 0; i < 2; ++i) {
        int r = n0 + w * 32 + i * 16 + (l >> 2);
        boff[i] = (size_t)r * D_IN + ((l & 3) ^ ((l >> 3) & 3)) * 8;   // bf16 units
    }

    f32x4 acc[4][4] = {};

    #define STAGE(buf, kk)                                                       \
        do {                                                                     \
            char* ab = (char*)As + (buf) * 16384 + w * 4096;                     \
            char* bb = (char*)Bs + (buf) * 8192  + w * 2048;                     \
            _Pragma("unroll")                                                    \
            for (int i = 0; i < 4; ++i) GLD16(&A[aoff[i] + (kk)], ab + i * 1024);\
            _Pragma("unroll")                                                    \
            for (int i = 0; i < 2; ++i) GLD16(&Wt[boff[i] + (kk)], bb + i * 1024);\
        } while (0)

    #define COMPUTE(buf)                                                         \
        do {                                                                     \
            const char* abase = (const char*)As + (buf) * 16384;                 \
            const char* bbase = (const char*)Bs + (buf) * 8192;                  \
            s8v af[4], bfr[4];                                                   \
            _Pragma("unroll")                                                    \
            for (int f = 0; f < 4; ++f) {                                        \
                int row = wm + f * 16 + lr;            /* row&7 == lr&7 */       \
                int s0  = (2 * lk) ^ (lr & 7);                                   \
                const char* pr = abase + row * 128;                              \
                float4 x0 = *(const float4*)(pr + s0 * 16);                      \
                float4 x1 = *(const float4*)(pr + (s0 ^ 1) * 16);                \
                union { s8v v; unsigned short h[8]; } u;                         \
                u.h[0] = bf16b(x0.x); u.h[1] = bf16b(x0.y);                      \
                u.h[2] = bf16b(x0.z); u.h[3] = bf16b(x0.w);                      \
                u.h[4] = bf16b(x1.x); u.h[5] = bf16b(x1.y);                      \
                u.h[6] = bf16b(x1.z); u.h[7] = bf16b(x1.w);                      \
                af[f] = u.v;                                                     \
            }                                                                    \
            _Pragma("unroll")                                                    \
            for (int f = 0; f < 4; ++f) {                                        \
                int row = wn + f * 16 + lr;        /* (row>>1)&3 == (lr>>1)&3 */ \
                int s   = lk ^ ((lr >> 1) & 3);                                  \
                bfr[f] = *(const s8v*)(bbase + row * 64 + s * 16);               \
            }                                                                    \
            _Pragma("unroll")                                                    \
            for (int fm = 0; fm < 4; ++fm)                                       \
                _Pragma("unroll")                                                \
                for (int fn = 0; fn < 4; ++fn)                                   \
                    acc[fm][fn] = __builtin_amdgcn_mfma_f32_16x16x32_bf16(       \
                        af[fm], bfr[fn], acc[fm][fn], 0, 0, 0);                  \
        } while (0)

    STAGE(0, 0);
    __syncthreads();                 // drains prologue stage (vmcnt(0) at barrier)

    #pragma unroll 1
    for (int tk = 0; tk < 15; ++tk) {
        STAGE((tk + 1) & 1, (tk + 1) * 32);   // prefetch next tile (other buffer)
        COMPUTE(tk & 1);                      // compute current
        __syncthreads();                      // drain prefetch + release buffer
    }
    COMPUTE(1);                               // tile 15, no further prefetch

    #undef STAGE
    #undef COMPUTE

    #pragma unroll
    for (int fm = 0; fm < 4; ++fm) {
        #pragma unroll
        for (int j = 0; j < 4; ++j) {
            int row = m0 + wm + fm * 16 + lk * 4 + j;
            if (row < N_NODES) {
                float s = dinv[row];
                #pragma unroll
                for (int fn = 0; fn < 4; ++fn) {
                    int col = n0 + wn + fn * 16 + lr;
                    yb[(size_t)row * D_OUT + col] = bf16b(acc[fm][fn][j] * s);
                }
            }
        }
    }
}

// ============ gather: out[c] = relu(dinv[c]*(yb[c] + sum yb[src]) + b) ============
// R7 eg-split layout (winner of R7/R8/R9 A/B): wave = 2 edge-groups x 32
// col-slots of 16B -> each load instruction moves 1KB covering TWO edges.
// Full rounds of 8 edges/half (16/wave) unmasked; tail = masked rounds of
// 4/half (clamped loads re-hit the last row's lines in L1 -> byte-cheap).
__device__ __forceinline__ void add8(float* acc, uint4 q) {
    unsigned x;
    x = q.x; acc[0] += bflo(x); acc[1] += bfhi(x);
    x = q.y; acc[2] += bflo(x); acc[3] += bfhi(x);
    x = q.z; acc[4] += bflo(x); acc[5] += bfhi(x);
    x = q.w; acc[6] += bflo(x); acc[7] += bfhi(x);
}

__launch_bounds__(256)
__global__ void k_gather(const int* __restrict__ row_ptr, const int* __restrict__ csr_src,
                         const unsigned short* __restrict__ yb, const float* __restrict__ dinv,
                         const float* __restrict__ bias, float* __restrict__ out)
{
    const int c  = blockIdx.x * 4 + (threadIdx.x >> 6);
    const int l  = threadIdx.x & 63;
    const int eg = l >> 5;              // edge-group 0/1
    const int cs = l & 31;              // col-slot: cols cs*8 .. cs*8+7
    const size_t colb = (size_t)cs * 8;

    float acc[8] = {0.f,0.f,0.f,0.f,0.f,0.f,0.f,0.f};

    const int s = row_ptr[c];
    const int e = row_ptr[c + 1];

    int i = s + eg;
    while (i + 14 < e) {                // 8 edges per half, unmasked
        int r[8];
        #pragma unroll
        for (int u = 0; u < 8; ++u) r[u] = csr_src[i + 2 * u];
        uint4 v[8];
        #pragma unroll
        for (int u = 0; u < 8; ++u) v[u] = *(const uint4*)&yb[(size_t)r[u] * D_OUT + colb];
        #pragma unroll
        for (int u = 0; u < 8; ++u) add8(acc, v[u]);
        i += 16;
    }
    while (i < e) {                     // masked rounds of 4 per half
        int r[4];
        #pragma unroll
        for (int u = 0; u < 4; ++u) {
            int p = i + 2 * u;
            r[u] = csr_src[p < e ? p : e - 1];
        }
        uint4 v[4];
        #pragma unroll
        for (int u = 0; u < 4; ++u) v[u] = *(const uint4*)&yb[(size_t)r[u] * D_OUT + colb];
        #pragma unroll
        for (int u = 0; u < 4; ++u)
            if (i + 2 * u < e) add8(acc, v[u]);
        i += 8;
    }

    // combine the two edge-group halves
    #pragma unroll
    for (int u = 0; u < 8; ++u) acc[u] += __shfl_xor(acc[u], 32, 64);

    // self-loop term
    uint4 sv = *(const uint4*)&yb[(size_t)c * D_OUT + colb];
    add8(acc, sv);

    if (eg == 0) {
        const float sc = dinv[c];
        float4 b0 = *(const float4*)&bias[colb];
        float4 b1 = *(const float4*)&bias[colb + 4];
        float4 o0, o1;
        o0.x = fmaxf(fmaf(acc[0], sc, b0.x), 0.f);
        o0.y = fmaxf(fmaf(acc[1], sc, b0.y), 0.f);
        o0.z = fmaxf(fmaf(acc[2], sc, b0.z), 0.f);
        o0.w = fmaxf(fmaf(acc[3], sc, b0.w), 0.f);
        o1.x = fmaxf(fmaf(acc[4], sc, b1.x), 0.f);
        o1.y = fmaxf(fmaf(acc[5], sc, b1.y), 0.f);
        o1.z = fmaxf(fmaf(acc[6], sc, b1.z), 0.f);
        o1.w = fmaxf(fmaf(acc[7], sc, b1.w), 0.f);
        float* dst = &out[(size_t)c * D_OUT + colb];
        *(float4*)dst       = o0;
        *(float4*)(dst + 4) = o1;
    }
}

extern "C" void kernel_launch(void* const* d_in, const int* in_sizes, int n_in,
                              void* d_out, int out_size, void* d_ws, size_t ws_size,
                              hipStream_t stream) {
    const float* x   = (const float*)d_in[0];
    const int*   ei  = (const int*)d_in[1];
    const float* W   = (const float*)d_in[2];
    const float* b   = (const float*)d_in[3];
    float*       out = (float*)d_out;

    const int* row = ei;
    const int* col = ei + N_EDGES;

    char* p = (char*)d_ws;
    unsigned short* yb = (unsigned short*)p;  p += (size_t)N_NODES * D_OUT * 2;   // 25.6 MB
    unsigned short* Wt = (unsigned short*)p;  p += (size_t)D_OUT * D_IN * 2;      // 256 KB
    int*   csr_src = (int*)p;                 p += (size_t)N_EDGES * 4;           // 3.2 MB
    int*   cnt     = (int*)p;                 p += (size_t)N_NODES * 4;
    int*   row_ptr = (int*)p;                 p += (size_t)(N_NODES + 4) * 4;
    int*   cursor  = (int*)p;                 p += (size_t)N_NODES * 4;
    float* dinv    = (float*)p;               p += (size_t)N_NODES * 4;
    int*   bsum    = (int*)p;                 p += (size_t)NBLK_SCAN * 4;
    int*   boff    = (int*)p;                 p += (size_t)NBLK_SCAN * 4;

    hipMemsetAsync(cnt, 0, (size_t)N_NODES * sizeof(int), stream);
    k_count<<<(N_EDGES + 255) / 256, 256, 0, stream>>>(col, cnt);
    k_scan1<<<NBLK_SCAN, 256, 0, stream>>>(cnt, bsum);
    k_scan2<<<1, 64, 0, stream>>>(bsum, boff);
    k_scan3<<<NBLK_SCAN, 256, 0, stream>>>(cnt, boff, row_ptr, dinv, cursor);
    k_fill <<<(N_EDGES + 255) / 256, 256, 0, stream>>>(row, col, cursor, csr_src);
    k_wt   <<<D_IN, D_OUT, 0, stream>>>(W, Wt);

    k_gemm<<<GEMM_NWG, 256, 0, stream>>>(x, Wt, dinv, yb);

    k_gather<<<N_NODES / 4, 256, 0, stream>>>(row_ptr, csr_src, yb, dinv, b, out);
}

// Round 11
// 209.151 us; speedup vs baseline: 1.0458x; 1.0458x over previous
//
#include <hip/hip_runtime.h>
#include <hip/hip_bf16.h>

#define N_NODES 50000
#define N_EDGES 800000
#define D_IN    512
#define D_OUT   256
#define NBLK_SCAN ((N_NODES + 1023) / 1024)   // 49
#define GEMM_NWG (((N_NODES + 127) / 128) * 2)  // 782
#define GEMM_Q   (GEMM_NWG / 8)                  // 97
#define GEMM_R   (GEMM_NWG % 8)                  // 6

typedef short s8v  __attribute__((ext_vector_type(8)));
typedef float f32x4 __attribute__((ext_vector_type(4)));

__device__ __forceinline__ unsigned short bf16b(float f) {
    __hip_bfloat16 h = __float2bfloat16(f);
    return *reinterpret_cast<unsigned short*>(&h);
}
__device__ __forceinline__ float bflo(unsigned u) { return __uint_as_float(u << 16); }
__device__ __forceinline__ float bfhi(unsigned u) { return __uint_as_float(u & 0xffff0000u); }

// global -> LDS direct copy, 16B per lane; LDS dest arg = wave-uniform base,
// HW adds lane*16.
#define GLD16(gp, lp)                                                           \
    __builtin_amdgcn_global_load_lds(                                           \
        (const __attribute__((address_space(1))) unsigned int*)(const void*)(gp),\
        (__attribute__((address_space(3))) unsigned int*)(void*)(lp), 16, 0, 0)

__device__ __forceinline__ int wave_incl_scan(int v, int lane) {
    #pragma unroll
    for (int d = 1; d < 64; d <<= 1) {
        int u = __shfl_up(v, d, 64);
        if (lane >= d) v += u;
    }
    return v;
}

// ============ CSR build ============

__global__ void k_count(const int* __restrict__ col, int* __restrict__ cnt) {
    int i = (blockIdx.x * 256 + threadIdx.x) * 2;
    if (i < N_EDGES) {                            // N_EDGES even
        int2 c = *(const int2*)&col[i];
        atomicAdd(&cnt[c.x], 1);
        atomicAdd(&cnt[c.y], 1);
    }
}

__launch_bounds__(256)
__global__ void k_scan1(const int* __restrict__ cnt, int* __restrict__ bsum) {
    const int t = threadIdx.x, b = blockIdx.x;
    const int idx = b * 1024 + t * 4;
    int4 v = make_int4(0, 0, 0, 0);
    if (idx < N_NODES) v = *(const int4*)&cnt[idx];
    int s = v.x + v.y + v.z + v.w;
    #pragma unroll
    for (int d = 1; d < 64; d <<= 1) s += __shfl_xor(s, d, 64);
    __shared__ int ws[4];
    if ((t & 63) == 0) ws[t >> 6] = s;
    __syncthreads();
    if (t == 0) bsum[b] = ws[0] + ws[1] + ws[2] + ws[3];
}

// in-block exclusive scan + self-computed block offset (scan2 merged in)
__launch_bounds__(256)
__global__ void k_scan3(const int* __restrict__ cnt, const int* __restrict__ bsum,
                        int* __restrict__ row_ptr, float* __restrict__ dinv,
                        int* __restrict__ cursor) {
    const int t = threadIdx.x, b = blockIdx.x;
    const int lane = t & 63, wv = t >> 6;
    const int idx = b * 1024 + t * 4;
    int4 v = make_int4(0, 0, 0, 0);
    if (idx < N_NODES) v = *(const int4*)&cnt[idx];
    int s = v.x + v.y + v.z + v.w;
    int isc = wave_incl_scan(s, lane);
    __shared__ int wsum[4];
    __shared__ int s_boff;
    if (lane == 63) wsum[wv] = isc;
    if (t < 64) {                                  // wave 0: sum of bsum[0..b)
        int u = (t < b) ? bsum[t] : 0;             // b <= 48 < 64
        #pragma unroll
        for (int d = 1; d < 64; d <<= 1) u += __shfl_xor(u, d, 64);
        if (t == 0) s_boff = u;
    }
    __syncthreads();
    int off = s_boff;
    #pragma unroll
    for (int i = 0; i < 4; ++i)
        if (i < wv) off += wsum[i];
    int p0 = off + isc - s;
    int p1 = p0 + v.x;
    int p2 = p1 + v.y;
    int p3 = p2 + v.z;
    if (idx < N_NODES) {
        row_ptr[idx + 0] = p0; cursor[idx + 0] = p0; dinv[idx + 0] = rsqrtf(1.f + (float)v.x);
        row_ptr[idx + 1] = p1; cursor[idx + 1] = p1; dinv[idx + 1] = rsqrtf(1.f + (float)v.y);
        row_ptr[idx + 2] = p2; cursor[idx + 2] = p2; dinv[idx + 2] = rsqrtf(1.f + (float)v.z);
        row_ptr[idx + 3] = p3; cursor[idx + 3] = p3; dinv[idx + 3] = rsqrtf(1.f + (float)v.w);
    }
    if (b == 0 && t == 0) row_ptr[N_NODES] = N_EDGES;
}

__global__ void k_fill(const int* __restrict__ row, const int* __restrict__ col,
                       int* __restrict__ cursor, int* __restrict__ csr_src) {
    int i = (blockIdx.x * 256 + threadIdx.x) * 2;
    if (i < N_EDGES) {
        int2 c = *(const int2*)&col[i];
        int2 r = *(const int2*)&row[i];
        int p0 = atomicAdd(&cursor[c.x], 1);
        csr_src[p0] = r.x;
        int p1 = atomicAdd(&cursor[c.y], 1);
        csr_src[p1] = r.y;
    }
}

// ============ W transpose + bf16 convert ============
__global__ void k_wt(const float* __restrict__ W, unsigned short* __restrict__ Wt) {
    int k = blockIdx.x;      // 512
    int n = threadIdx.x;     // 256
    Wt[(size_t)n * D_IN + k] = bf16b(W[(size_t)k * D_OUT + n]);
}

// ============ MFMA GEMM: yb = bf16(dinv[r] * (x @ W)) ============
// Round-10 lesson: 48KB dbuf -> 3 blocks/CU -> per-step barrier drain (~HBM
// latency) had nothing to hide behind -> 10K cyc/step stall. Fix = block-level
// TLP: SINGLE 24KB buffer (A fp32 16KB + B bf16 8KB) -> 6 blocks/CU, 24
// waves/CU; one block's stage stall hides under the other 5 blocks' compute.
// Swizzles (conflict-free, quarter-wave rule):
//  A rows 128B (8 slots): stored slot s of row r = logical s^(r&7).
//  B rows  64B (4 slots): stored slot s of row r = logical s^((r>>1)&3).
__launch_bounds__(256)
__global__ void k_gemm(const float* __restrict__ A,            // [N_NODES,512] fp32
                       const unsigned short* __restrict__ Wt,  // [256,512] bf16
                       const float* __restrict__ dinv,
                       unsigned short* __restrict__ yb)        // [N_NODES,256] bf16
{
    __shared__ __align__(16) float          As[128 * 32];   // 16 KB
    __shared__ __align__(16) unsigned short Bs[128 * 32];   // 8 KB

    // bijective XCD swizzle (m204)
    int orig = blockIdx.x;
    int xcd = orig % 8, pos = orig / 8;
    int wg = (xcd < GEMM_R) ? xcd * (GEMM_Q + 1) + pos
                            : GEMM_R * (GEMM_Q + 1) + (xcd - GEMM_R) * GEMM_Q + pos;
    const int nt = wg & 1;
    const int mt = wg >> 1;
    const int m0 = mt * 128;
    const int n0 = nt * 128;

    const int t  = threadIdx.x;
    const int w  = t >> 6;
    const int l  = t & 63;
    const int wm = (w >> 1) * 64;
    const int wn = (w & 1) * 64;
    const int lr = l & 15;
    const int lk = l >> 4;

    // A staging: 4 GLDs/wave; GLD i covers LDS rows w*32+i*8+(l>>3),
    // stored slot l&7 <- source slot (l&7)^(l>>3)
    size_t aoff[4];
    #pragma unroll
    for (int i = 0; i < 4; ++i) {
        int r = m0 + w * 32 + i * 8 + (l >> 3);
        if (r >= N_NODES) r = 0;                 // tail clamp; outputs guarded
        aoff[i] = (size_t)r * D_IN + ((l & 7) ^ (l >> 3)) * 4;   // float units
    }
    // B staging: 2 GLDs/wave; GLD i covers rows w*32+i*16+(l>>2),
    // stored slot l&3 <- source slot (l&3)^((l>>3)&3)
    size_t boff[2];
    #pragma unroll
    for (int i = 0; i < 2; ++i) {
        int r = n0 + w * 32 + i * 16 + (l >> 2);
        boff[i] = (size_t)r * D_IN + ((l & 3) ^ ((l >> 3) & 3)) * 8;   // bf16 units
    }

    f32x4 acc[4][4] = {};

    #pragma unroll 1
    for (int tk = 0; tk < 16; ++tk) {
        const int kk = tk * 32;
        {   // stage
            char* ab = (char*)As + w * 4096;
            char* bb = (char*)Bs + w * 2048;
            #pragma unroll
            for (int i = 0; i < 4; ++i) GLD16(&A[aoff[i] + kk], ab + i * 1024);
            #pragma unroll
            for (int i = 0; i < 2; ++i) GLD16(&Wt[boff[i] + kk], bb + i * 1024);
        }
        __syncthreads();
        {   // compute
            s8v af[4], bfr[4];
            #pragma unroll
            for (int f = 0; f < 4; ++f) {
                int row = wm + f * 16 + lr;            // row&7 == lr&7
                int s0  = (2 * lk) ^ (lr & 7);
                const char* pr = (const char*)As + row * 128;
                float4 x0 = *(const float4*)(pr + s0 * 16);
                float4 x1 = *(const float4*)(pr + (s0 ^ 1) * 16);
                union { s8v v; unsigned short h[8]; } u;
                u.h[0] = bf16b(x0.x); u.h[1] = bf16b(x0.y);
                u.h[2] = bf16b(x0.z); u.h[3] = bf16b(x0.w);
                u.h[4] = bf16b(x1.x); u.h[5] = bf16b(x1.y);
                u.h[6] = bf16b(x1.z); u.h[7] = bf16b(x1.w);
                af[f] = u.v;
            }
            #pragma unroll
            for (int f = 0; f < 4; ++f) {
                int row = wn + f * 16 + lr;        // (row>>1)&3 == (lr>>1)&3
                int s   = lk ^ ((lr >> 1) & 3);
                bfr[f] = *(const s8v*)((const char*)Bs + row * 64 + s * 16);
            }
            #pragma unroll
            for (int fm = 0; fm < 4; ++fm)
                #pragma unroll
                for (int fn = 0; fn < 4; ++fn)
                    acc[fm][fn] = __builtin_amdgcn_mfma_f32_16x16x32_bf16(
                        af[fm], bfr[fn], acc[fm][fn], 0, 0, 0);
        }
        __syncthreads();
    }

    #pragma unroll
    for (int fm = 0; fm < 4; ++fm) {
        #pragma unroll
        for (int j = 0; j < 4; ++j) {
            int row = m0 + wm + fm * 16 + lk * 4 + j;
            if (row < N_NODES) {
                float s = dinv[row];
                #pragma unroll
                for (int fn = 0; fn < 4; ++fn) {
                    int col = n0 + wn + fn * 16 + lr;
                    yb[(size_t)row * D_OUT + col] = bf16b(acc[fm][fn][j] * s);
                }
            }
        }
    }
}

// ============ gather: out[c] = relu(dinv[c]*(yb[c] + sum yb[src]) + b) ============
// eg-split layout: wave = 2 edge-groups x 32 col-slots of 16B -> each load
// instruction moves 1KB covering TWO edges. Full rounds of 8 edges/half
// unmasked; tail = masked rounds of 4/half (clamped loads are L1-cheap).
__device__ __forceinline__ void add8(float* acc, uint4 q) {
    unsigned x;
    x = q.x; acc[0] += bflo(x); acc[1] += bfhi(x);
    x = q.y; acc[2] += bflo(x); acc[3] += bfhi(x);
    x = q.z; acc[4] += bflo(x); acc[5] += bfhi(x);
    x = q.w; acc[6] += bflo(x); acc[7] += bfhi(x);
}

__launch_bounds__(256)
__global__ void k_gather(const int* __restrict__ row_ptr, const int* __restrict__ csr_src,
                         const unsigned short* __restrict__ yb, const float* __restrict__ dinv,
                         const float* __restrict__ bias, float* __restrict__ out)
{
    const int c  = blockIdx.x * 4 + (threadIdx.x >> 6);
    const int l  = threadIdx.x & 63;
    const int eg = l >> 5;              // edge-group 0/1
    const int cs = l & 31;              // col-slot: cols cs*8 .. cs*8+7
    const size_t colb = (size_t)cs * 8;

    float acc[8] = {0.f,0.f,0.f,0.f,0.f,0.f,0.f,0.f};

    const int s = row_ptr[c];
    const int e = row_ptr[c + 1];

    int i = s + eg;
    while (i + 14 < e) {                // 8 edges per half, unmasked
        int r[8];
        #pragma unroll
        for (int u = 0; u < 8; ++u) r[u] = csr_src[i + 2 * u];
        uint4 v[8];
        #pragma unroll
        for (int u = 0; u < 8; ++u) v[u] = *(const uint4*)&yb[(size_t)r[u] * D_OUT + colb];
        #pragma unroll
        for (int u = 0; u < 8; ++u) add8(acc, v[u]);
        i += 16;
    }
    while (i < e) {                     // masked rounds of 4 per half
        int r[4];
        #pragma unroll
        for (int u = 0; u < 4; ++u) {
            int p = i + 2 * u;
            r[u] = csr_src[p < e ? p : e - 1];
        }
        uint4 v[4];
        #pragma unroll
        for (int u = 0; u < 4; ++u) v[u] = *(const uint4*)&yb[(size_t)r[u] * D_OUT + colb];
        #pragma unroll
        for (int u = 0; u < 4; ++u)
            if (i + 2 * u < e) add8(acc, v[u]);
        i += 8;
    }

    // combine the two edge-group halves
    #pragma unroll
    for (int u = 0; u < 8; ++u) acc[u] += __shfl_xor(acc[u], 32, 64);

    // self-loop term
    uint4 sv = *(const uint4*)&yb[(size_t)c * D_OUT + colb];
    add8(acc, sv);

    if (eg == 0) {
        const float sc = dinv[c];
        float4 b0 = *(const float4*)&bias[colb];
        float4 b1 = *(const float4*)&bias[colb + 4];
        float4 o0, o1;
        o0.x = fmaxf(fmaf(acc[0], sc, b0.x), 0.f);
        o0.y = fmaxf(fmaf(acc[1], sc, b0.y), 0.f);
        o0.z = fmaxf(fmaf(acc[2], sc, b0.z), 0.f);
        o0.w = fmaxf(fmaf(acc[3], sc, b0.w), 0.f);
        o1.x = fmaxf(fmaf(acc[4], sc, b1.x), 0.f);
        o1.y = fmaxf(fmaf(acc[5], sc, b1.y), 0.f);
        o1.z = fmaxf(fmaf(acc[6], sc, b1.z), 0.f);
        o1.w = fmaxf(fmaf(acc[7], sc, b1.w), 0.f);
        float* dst = &out[(size_t)c * D_OUT + colb];
        *(float4*)dst       = o0;
        *(float4*)(dst + 4) = o1;
    }
}

extern "C" void kernel_launch(void* const* d_in, const int* in_sizes, int n_in,
                              void* d_out, int out_size, void* d_ws, size_t ws_size,
                              hipStream_t stream) {
    const float* x   = (const float*)d_in[0];
    const int*   ei  = (const int*)d_in[1];
    const float* W   = (const float*)d_in[2];
    const float* b   = (const float*)d_in[3];
    float*       out = (float*)d_out;

    const int* row = ei;
    const int* col = ei + N_EDGES;

    char* p = (char*)d_ws;
    unsigned short* yb = (unsigned short*)p;  p += (size_t)N_NODES * D_OUT * 2;   // 25.6 MB
    unsigned short* Wt = (unsigned short*)p;  p += (size_t)D_OUT * D_IN * 2;      // 256 KB
    int*   csr_src = (int*)p;                 p += (size_t)N_EDGES * 4;           // 3.2 MB
    int*   cnt     = (int*)p;                 p += (size_t)N_NODES * 4;
    int*   row_ptr = (int*)p;                 p += (size_t)(N_NODES + 4) * 4;
    int*   cursor  = (int*)p;                 p += (size_t)N_NODES * 4;
    float* dinv    = (float*)p;               p += (size_t)N_NODES * 4;
    int*   bsum    = (int*)p;                 p += (size_t)NBLK_SCAN * 4;

    hipMemsetAsync(cnt, 0, (size_t)N_NODES * sizeof(int), stream);
    k_count<<<(N_EDGES / 2 + 255) / 256, 256, 0, stream>>>(col, cnt);
    k_scan1<<<NBLK_SCAN, 256, 0, stream>>>(cnt, bsum);
    k_scan3<<<NBLK_SCAN, 256, 0, stream>>>(cnt, bsum, row_ptr, dinv, cursor);
    k_fill <<<(N_EDGES / 2 + 255) / 256, 256, 0, stream>>>(row, col, cursor, csr_src);
    k_wt   <<<D_IN, D_OUT, 0, stream>>>(W, Wt);

    k_gemm<<<GEMM_NWG, 256, 0, stream>>>(x, Wt, dinv, yb);

    k_gather<<<N_NODES / 4, 256, 0, stream>>>(row_ptr, csr_src, yb, dinv, b, out);
}